// Round 11
// baseline (283.771 us; speedup 1.0000x reference)
//
#include <hip/hip_runtime.h>

#define N 8192
#define IOU_THR 0.5f
#define SIGMA 0.2f
#define BETA 0.6f
#define EPSF 1e-8f
#define SCORE_FLOOR 0.01f
#define PAIR_BUF 2048
#define TCAP 16384          // CSR capacity in k_nms LDS (measured T ~= 6-9K)

__device__ __forceinline__ float iou_f(float4 a, float4 b) {
    float x1 = fmaxf(a.x, b.x);
    float y1 = fmaxf(a.y, b.y);
    float x2 = fminf(a.z, b.z);
    float y2 = fminf(a.w, b.w);
    float inter = fmaxf(x2 - x1, 0.0f) * fmaxf(y2 - y1, 0.0f);
    float aa = (a.z - a.x) * (a.w - a.y);
    float ab = (b.z - b.x) * (b.w - b.y);
    return inter / (aa + ab - inter + EPSF);
}

__device__ __forceinline__ float diou_f(float4 a, float4 b) {
    float x1 = fmaxf(a.x, b.x);
    float y1 = fmaxf(a.y, b.y);
    float x2 = fminf(a.z, b.z);
    float y2 = fminf(a.w, b.w);
    float inter = fmaxf(x2 - x1, 0.0f) * fmaxf(y2 - y1, 0.0f);
    float a1 = (a.z - a.x) * (a.w - a.y);
    float a2 = (b.z - b.x) * (b.w - b.y);
    float iou = inter / (a1 + a2 - inter + EPSF);
    float cx1 = (a.x + a.z) * 0.5f, cy1 = (a.y + a.w) * 0.5f;
    float cx2 = (b.x + b.z) * 0.5f, cy2 = (b.y + b.w) * 0.5f;
    float dx = cx1 - cx2, dy = cy1 - cy2;
    float cdist = dx * dx + dy * dy;
    float ex1 = fminf(a.x, b.x), ey1 = fminf(a.y, b.y);
    float ex2 = fmaxf(a.z, b.z), ey2 = fmaxf(a.w, b.w);
    float ew = ex2 - ex1, eh = ey2 - ey1;
    float edist = ew * ew + eh * eh;
    return iou - cdist / (edist + EPSF);
}

// ---- top-4 boxes by key (score desc, idx asc) + zero pair counter ----------
// key = (~score_bits)<<32 | idx; 4 min-reductions with exclusion.
__global__ __launch_bounds__(256) void k_top4(const float* __restrict__ scores,
                                              const float4* __restrict__ boxes,
                                              float4* __restrict__ t4,
                                              int* __restrict__ counter) {
    __shared__ unsigned long long red[256];
    int tid = threadIdx.x;
    unsigned long long sel[4];
    for (int k = 0; k < 4; ++k) {
        unsigned long long best = ~0ull;
        for (int q = 0; q < 32; ++q) {
            int i = q * 256 + tid;
            unsigned sb = __float_as_uint(scores[i]);
            unsigned long long key = ((unsigned long long)(~sb) << 32) | (unsigned)i;
            bool used = false;
            for (int m = 0; m < k; ++m) used |= (key == sel[m]);
            if (!used && key < best) best = key;
        }
        red[tid] = best;
        __syncthreads();
        for (int off = 128; off > 0; off >>= 1) {
            if (tid < off) {
                unsigned long long o = red[tid + off];
                if (o < red[tid]) red[tid] = o;
            }
            __syncthreads();
        }
        sel[k] = red[0];
        __syncthreads();
    }
    if (tid < 4) t4[tid] = boxes[(unsigned)(sel[tid] & 0xffffffffull)];
    if (tid == 0) counter[0] = 0;
}

// ---- pairs in ORIGINAL index space: iou test + total, unordered append -----
// pseudo_u = [iou(b_u, t4[0..3])] (component order = rank order). diou is
// symmetric, so operand order is free.
// src = better-keyed endpoint (score desc, idx asc); entry = (src<<13)|tgt.
__global__ __launch_bounds__(256) void k_pairs(const float4* __restrict__ b,
                                               const float* __restrict__ scores,
                                               const float4* __restrict__ t4,
                                               int* __restrict__ counter,
                                               int2* __restrict__ adj, int cap) {
    int tj = blockIdx.x, ti = blockIdx.y;
    if (tj < ti) return;
    __shared__ float4 bj[256];
    __shared__ float4 pj[256];
    __shared__ float sj[256];
    __shared__ int2 lbuf[PAIR_BUF];
    __shared__ int lcount, lbase;
    int tid = threadIdx.x;
    if (tid == 0) lcount = 0;
    float4 t0 = t4[0], t1 = t4[1], t2 = t4[2], t3 = t4[3];
    int jbase = tj * 256;
    float4 bjv = b[jbase + tid];
    bj[tid] = bjv;
    sj[tid] = scores[jbase + tid];
    float4 pjv;
    pjv.x = iou_f(bjv, t0); pjv.y = iou_f(bjv, t1);
    pjv.z = iou_f(bjv, t2); pjv.w = iou_f(bjv, t3);
    pj[tid] = pjv;
    __syncthreads();
    int i = ti * 256 + tid;
    float4 bi = b[i];
    float si = scores[i];
    float4 pi;
    pi.x = iou_f(bi, t0); pi.y = iou_f(bi, t1);
    pi.z = iou_f(bi, t2); pi.w = iou_f(bi, t3);
    for (int jj = 0; jj < 256; ++jj) {
        int j = jbase + jj;
        if (j <= i) continue;
        float v = iou_f(bi, bj[jj]);
        if (v > IOU_THR) {
            float penalty = expf(-(v * v) / SIGMA);
            float d = diou_f(pi, pj[jj]);
            float total = fminf(penalty + (d * d) / BETA, 1.0f);
            // i < j always; tie (si==sj) -> src = smaller idx = i
            int src, tgt;
            if (si >= sj[jj]) { src = i; tgt = j; } else { src = j; tgt = i; }
            int pos = atomicAdd(&lcount, 1);
            if (pos < PAIR_BUF) {
                int2 e;
                e.x = (src << 13) | tgt;
                e.y = __float_as_int(total);
                lbuf[pos] = e;
            }
        }
    }
    __syncthreads();
    if (tid == 0) {
        int c = lcount;
        if (c > PAIR_BUF) c = PAIR_BUF;
        lcount = c;
        lbase = c ? atomicAdd(counter, c) : 0;
    }
    __syncthreads();
    int c = lcount, base = lbase;
    for (int t = tid; t < c; t += 256) {
        int slot = base + t;
        if (slot < cap) adj[slot] = lbuf[t];
    }
}

// ---- nms: order-free fate propagation over CSR-by-target (original idx) ----
// Factors <= 1 => prefix products decrease => box dies iff >=1 final-alive
// source AND score * prod(alive factors) < floor. Monotone 3-state iteration;
// min-key undecided box always decides => termination. Per-box base score +
// segment bounds cached in registers; 4 barrier-free inner passes per check
// (stale UNK reads only delay decisions, never corrupt them).
__global__ __launch_bounds__(512) void k_nms(const int2* __restrict__ adj,
                                             const int* __restrict__ counter,
                                             const float* __restrict__ scores,
                                             float* __restrict__ out, int cap) {
    __shared__ unsigned short idx16[TCAP];   // 32KB  src per entry
    __shared__ float fac[TCAP];              // 64KB  factor per entry
    __shared__ int starts[N];                // 32KB  counts -> excl -> ends
    __shared__ unsigned char state[N];       // 8KB   0=UNK 1=ALIVE 2=DEAD
    __shared__ int wsum[8];
    int tid = threadIdx.x;
    int T = counter[0];
    if (T > cap) T = cap;
    if (T > TCAP) T = TCAP;

    for (int r = tid; r < N; r += 512) { starts[r] = 0; state[r] = 0; }
    __syncthreads();

    // count per target
    for (int s = 0; s < 32; ++s) {
        int g = s * 512 + tid;
        if (g < T) atomicAdd(&starts[adj[g].x & 8191], 1);
    }
    __syncthreads();

    // exclusive scan of starts[8192] (512 threads x 16, shuffle scan)
    int loc[16];
    int base16 = tid * 16;
    int sum = 0;
#pragma unroll
    for (int q = 0; q < 16; ++q) { loc[q] = starts[base16 + q]; sum += loc[q]; }
    int lane = tid & 63, wv = tid >> 6;
    int v = sum;
    for (int off = 1; off < 64; off <<= 1) {
        int u = __shfl_up(v, off);
        if (lane >= off) v += u;
    }
    if (lane == 63) wsum[wv] = v;
    __syncthreads();
    if (tid < 8) {
        int x = wsum[tid];
        for (int off = 1; off < 8; off <<= 1) {
            int u = __shfl_up(x, off);
            if (tid >= off) x += u;
        }
        wsum[tid] = x;
    }
    __syncthreads();
    int excl = ((wv == 0) ? 0 : wsum[wv - 1]) + (v - sum);
#pragma unroll
    for (int q = 0; q < 16; ++q) { starts[base16 + q] = excl; excl += loc[q]; }
    __syncthreads();

    // fill (starts[j] advances to end; start_j = j ? starts[j-1] : 0 after)
    for (int s = 0; s < 32; ++s) {
        int g = s * 512 + tid;
        if (g < T) {
            int2 e = adj[g];
            int pos = atomicAdd(&starts[e.x & 8191], 1);
            idx16[pos] = (unsigned short)(((unsigned)e.x) >> 13);
            fac[pos] = __int_as_float(e.y);
        }
    }
    __syncthreads();

    // register cache: base score + segment bounds per owned box
    float base[16];
    int rs0[16], rs1[16];
    unsigned int undec = 0xffffu;
#pragma unroll
    for (int k = 0; k < 16; ++k) {
        int j = k * 512 + tid;
        base[k] = scores[j];
        rs1[k] = starts[j];
        rs0[k] = j ? starts[j - 1] : 0;
    }

    int iter = 0;
    while (true) {
        for (int pass = 0; pass < 4; ++pass) {
#pragma unroll
            for (int k = 0; k < 16; ++k) {
                if (!(undec & (1u << k))) continue;
                int j = k * 512 + tid;
                float P = base[k];
                bool unk = false, dead = false;
                int e1 = rs1[k];
                for (int e = rs0[k]; e < e1; ++e) {
                    unsigned char st = state[idx16[e]];
                    if (st == 1) {
                        P *= fac[e];
                        if (P < SCORE_FLOOR) { dead = true; break; }
                    } else if (st == 0) {
                        unk = true;
                    }
                }
                if (dead) {
                    state[j] = 2;
                    out[j] = P;
                    out[N + j] = 0.0f;
                    undec &= ~(1u << k);
                } else if (!unk) {
                    state[j] = 1;
                    out[j] = P;
                    out[N + j] = 1.0f;
                    undec &= ~(1u << k);
                }
            }
        }
        if (__syncthreads_count((int)(undec != 0u)) == 0) break;
        if (++iter > 2048) break;   // safety against unforeseen corruption
    }
}

extern "C" void kernel_launch(void* const* d_in, const int* in_sizes, int n_in,
                              void* d_out, int out_size, void* d_ws, size_t ws_size,
                              hipStream_t stream) {
    const float4* boxes = (const float4*)d_in[0];
    const float* scores = (const float*)d_in[1];
    float* out = (float*)d_out;
    char* ws = (char*)d_ws;

    float4* t4 = (float4*)ws;                 // 64B
    int* counter = (int*)(ws + 64);           // 4B
    int2* adj = (int2*)(ws + 4096);

    long long avail = ((long long)ws_size - 4096) / 8;
    if (avail < 0) avail = 0;
    int cap = TCAP;
    if (avail < cap) cap = (int)avail;

    hipLaunchKernelGGL(k_top4, dim3(1), dim3(256), 0, stream, scores, boxes, t4, counter);
    hipLaunchKernelGGL(k_pairs, dim3(32, 32), dim3(256), 0, stream,
                       boxes, scores, t4, counter, adj, cap);
    hipLaunchKernelGGL(k_nms, dim3(1), dim3(512), 0, stream,
                       adj, counter, scores, out, cap);
}

// Round 12
// 252.816 us; speedup vs baseline: 1.1224x; 1.1224x over previous
//
#include <hip/hip_runtime.h>

#define N 8192
#define IOU_THR 0.5f
#define SIGMA 0.2f
#define BETA 0.6f
#define EPSF 1e-8f
#define SCORE_FLOOR 0.01f
#define PAIR_BUF 2048
#define TCAP 16384          // edge capacity (measured T ~= 6-9K)

__device__ __forceinline__ float iou_f(float4 a, float4 b) {
    float x1 = fmaxf(a.x, b.x);
    float y1 = fmaxf(a.y, b.y);
    float x2 = fminf(a.z, b.z);
    float y2 = fminf(a.w, b.w);
    float inter = fmaxf(x2 - x1, 0.0f) * fmaxf(y2 - y1, 0.0f);
    float aa = (a.z - a.x) * (a.w - a.y);
    float ab = (b.z - b.x) * (b.w - b.y);
    return inter / (aa + ab - inter + EPSF);
}

__device__ __forceinline__ float diou_f(float4 a, float4 b) {
    float x1 = fmaxf(a.x, b.x);
    float y1 = fmaxf(a.y, b.y);
    float x2 = fminf(a.z, b.z);
    float y2 = fminf(a.w, b.w);
    float inter = fmaxf(x2 - x1, 0.0f) * fmaxf(y2 - y1, 0.0f);
    float a1 = (a.z - a.x) * (a.w - a.y);
    float a2 = (b.z - b.x) * (b.w - b.y);
    float iou = inter / (a1 + a2 - inter + EPSF);
    float cx1 = (a.x + a.z) * 0.5f, cy1 = (a.y + a.w) * 0.5f;
    float cx2 = (b.x + b.z) * 0.5f, cy2 = (b.y + b.w) * 0.5f;
    float dx = cx1 - cx2, dy = cy1 - cy2;
    float cdist = dx * dx + dy * dy;
    float ex1 = fminf(a.x, b.x), ey1 = fminf(a.y, b.y);
    float ex2 = fmaxf(a.z, b.z), ey2 = fmaxf(a.w, b.w);
    float ew = ex2 - ex1, eh = ey2 - ey1;
    float edist = ew * ew + eh * eh;
    return iou - cdist / (edist + EPSF);
}

// ---- top-4 boxes by key (score desc, idx asc) + zero pair counter ----------
// (verbatim, passed rounds 11)
__global__ __launch_bounds__(256) void k_top4(const float* __restrict__ scores,
                                              const float4* __restrict__ boxes,
                                              float4* __restrict__ t4,
                                              int* __restrict__ counter) {
    __shared__ unsigned long long red[256];
    int tid = threadIdx.x;
    unsigned long long sel[4];
    for (int k = 0; k < 4; ++k) {
        unsigned long long best = ~0ull;
        for (int q = 0; q < 32; ++q) {
            int i = q * 256 + tid;
            unsigned sb = __float_as_uint(scores[i]);
            unsigned long long key = ((unsigned long long)(~sb) << 32) | (unsigned)i;
            bool used = false;
            for (int m = 0; m < k; ++m) used |= (key == sel[m]);
            if (!used && key < best) best = key;
        }
        red[tid] = best;
        __syncthreads();
        for (int off = 128; off > 0; off >>= 1) {
            if (tid < off) {
                unsigned long long o = red[tid + off];
                if (o < red[tid]) red[tid] = o;
            }
            __syncthreads();
        }
        sel[k] = red[0];
        __syncthreads();
    }
    if (tid < 4) t4[tid] = boxes[(unsigned)(sel[tid] & 0xffffffffull)];
    if (tid == 0) counter[0] = 0;
}

// ---- pairs in ORIGINAL index space (verbatim, passed round 11) -------------
__global__ __launch_bounds__(256) void k_pairs(const float4* __restrict__ b,
                                               const float* __restrict__ scores,
                                               const float4* __restrict__ t4,
                                               int* __restrict__ counter,
                                               int2* __restrict__ adj, int cap) {
    int tj = blockIdx.x, ti = blockIdx.y;
    if (tj < ti) return;
    __shared__ float4 bj[256];
    __shared__ float4 pj[256];
    __shared__ float sj[256];
    __shared__ int2 lbuf[PAIR_BUF];
    __shared__ int lcount, lbase;
    int tid = threadIdx.x;
    if (tid == 0) lcount = 0;
    float4 t0 = t4[0], t1 = t4[1], t2 = t4[2], t3 = t4[3];
    int jbase = tj * 256;
    float4 bjv = b[jbase + tid];
    bj[tid] = bjv;
    sj[tid] = scores[jbase + tid];
    float4 pjv;
    pjv.x = iou_f(bjv, t0); pjv.y = iou_f(bjv, t1);
    pjv.z = iou_f(bjv, t2); pjv.w = iou_f(bjv, t3);
    pj[tid] = pjv;
    __syncthreads();
    int i = ti * 256 + tid;
    float4 bi = b[i];
    float si = scores[i];
    float4 pi;
    pi.x = iou_f(bi, t0); pi.y = iou_f(bi, t1);
    pi.z = iou_f(bi, t2); pi.w = iou_f(bi, t3);
    for (int jj = 0; jj < 256; ++jj) {
        int j = jbase + jj;
        if (j <= i) continue;
        float v = iou_f(bi, bj[jj]);
        if (v > IOU_THR) {
            float penalty = expf(-(v * v) / SIGMA);
            float d = diou_f(pi, pj[jj]);
            float total = fminf(penalty + (d * d) / BETA, 1.0f);
            int src, tgt;
            if (si >= sj[jj]) { src = i; tgt = j; } else { src = j; tgt = i; }
            int pos = atomicAdd(&lcount, 1);
            if (pos < PAIR_BUF) {
                int2 e;
                e.x = (src << 13) | tgt;
                e.y = __float_as_int(total);
                lbuf[pos] = e;
            }
        }
    }
    __syncthreads();
    if (tid == 0) {
        int c = lcount;
        if (c > PAIR_BUF) c = PAIR_BUF;
        lcount = c;
        lbase = c ? atomicAdd(counter, c) : 0;
    }
    __syncthreads();
    int c = lcount, base = lbase;
    for (int t = tid; t < c; t += 256) {
        int slot = base + t;
        if (slot < cap) adj[slot] = lbuf[t];
    }
}

// ---- nms: push-based topological fate propagation (O(T) edge work) ---------
// pending[tgt] = undecided in-degree (bit31 = an alive source touched).
// Decided box's out-edges processed ONCE: alive src -> CAS-mul prod[tgt] +
// set bit31; all srcs -> atomicSub pending. The unique lane whose sub zeroes
// pending decides tgt (LDS FIFO: every lane's CAS/OR precedes its own sub,
// and the decider's sub is last => all contributions visible). Queue holds
// decided boxes with out-degree>0; rounds are barrier-paced (depth ~10-30).
// ALIVE iff !(touched && P<floor). Dead scores <0.01 both here and in ref.
__global__ __launch_bounds__(512) void k_nms(const int2* __restrict__ adj,
                                             const int* __restrict__ counter,
                                             const float* __restrict__ scores,
                                             float* __restrict__ out, int cap) {
    __shared__ unsigned int A1[N];            // cntOut -> cursor -> prod bits
    __shared__ unsigned int pend[N];          // cntIn -> pending | bit31
    __shared__ unsigned short starts16[N + 2];
    __shared__ unsigned short perm[TCAP];
    __shared__ unsigned char state8[N];       // 0 UNK / 1 ALIVE / 2 DEAD
    __shared__ unsigned short queue[N];
    __shared__ int qh, qt, wsum[8];
    int tid = threadIdx.x;
    int T = counter[0];
    if (T > cap) T = cap;
    if (T > TCAP) T = TCAP;
    if (tid == 0) { qh = 0; qt = 0; }
    for (int r = tid; r < N; r += 512) { A1[r] = 0u; pend[r] = 0u; }
    __syncthreads();

    // out-degree per src, in-degree per tgt
    for (int g = tid; g < T; g += 512) {
        unsigned ex = (unsigned)adj[g].x;
        atomicAdd(&A1[ex >> 13], 1u);
        atomicAdd(&pend[ex & 8191u], 1u);
    }
    __syncthreads();

    // exclusive scan of out-degrees -> starts16 + cursor(A1)
    unsigned loc[16];
    int b16 = tid * 16;
    unsigned sum = 0;
#pragma unroll
    for (int q = 0; q < 16; ++q) { loc[q] = A1[b16 + q]; sum += loc[q]; }
    int lane = tid & 63, wv = tid >> 6;
    unsigned v = sum;
    for (int off = 1; off < 64; off <<= 1) {
        unsigned u = (unsigned)__shfl_up((int)v, off);
        if (lane >= off) v += u;
    }
    if (lane == 63) wsum[wv] = (int)v;
    __syncthreads();
    if (tid < 8) {
        int x = wsum[tid];
        for (int off = 1; off < 8; off <<= 1) {
            int u = __shfl_up(x, off);
            if (tid >= off) x += u;
        }
        wsum[tid] = x;
    }
    __syncthreads();
    unsigned excl = (unsigned)((wv == 0) ? 0 : wsum[wv - 1]) + (v - sum);
#pragma unroll
    for (int q = 0; q < 16; ++q) {
        starts16[b16 + q] = (unsigned short)excl;
        A1[b16 + q] = excl;
        excl += loc[q];
    }
    if (tid == 511) starts16[N] = (unsigned short)excl;   // == T <= 16384
    __syncthreads();

    // fill perm (cursor advances in A1)
    for (int g = tid; g < T; g += 512) {
        unsigned ex = (unsigned)adj[g].x;
        unsigned pos = atomicAdd(&A1[ex >> 13], 1u);
        perm[pos] = (unsigned short)g;
    }
    __syncthreads();

    // init prod/state; seed = in-degree-0 boxes (aggregated enqueue)
    float* prod = (float*)A1;
    int seedCnt = 0;
#pragma unroll
    for (int k = 0; k < 16; ++k) {
        int r = k * 512 + tid;
        float s = scores[r];
        prod[r] = s;
        if (pend[r] == 0u) {
            state8[r] = 1;
            out[r] = s;
            out[N + r] = 1.0f;
            if (starts16[r] != starts16[r + 1]) ++seedCnt;   // only if out-edges
        } else {
            state8[r] = 0;
        }
    }
    // scan seed counts for queue bases
    {
        int vv = seedCnt;
        for (int off = 1; off < 64; off <<= 1) {
            int u = __shfl_up(vv, off);
            if (lane >= off) vv += u;
        }
        if (lane == 63) wsum[wv] = vv;
        __syncthreads();
        if (tid < 8) {
            int x = wsum[tid];
            for (int off = 1; off < 8; off <<= 1) {
                int u = __shfl_up(x, off);
                if (tid >= off) x += u;
            }
            wsum[tid] = x;
        }
        __syncthreads();
        int base = ((wv == 0) ? 0 : wsum[wv - 1]) + (vv - seedCnt);
#pragma unroll
        for (int k = 0; k < 16; ++k) {
            int r = k * 512 + tid;
            if (pend[r] == 0u && starts16[r] != starts16[r + 1])
                queue[base++] = (unsigned short)r;
        }
        if (tid == 511) qt = base;
    }
    __syncthreads();

    // barrier-paced rounds over the frontier queue
    int rounds = 0;
    while (true) {
        int h = qh, t = qt;
        if (h >= t || ++rounds > 2500) break;
        for (int q = h + tid; q < t; q += 512) {
            int s = queue[q];
            bool alive = (state8[s] == 1);
            int e0 = starts16[s], e1 = starts16[s + 1];
            for (int e = e0; e < e1; ++e) {
                int2 ed = adj[perm[e]];
                unsigned tgt = ((unsigned)ed.x) & 8191u;
                if (alive) {
                    float f = __int_as_float(ed.y);
                    unsigned* up = &A1[tgt];
                    unsigned cur = *(volatile unsigned*)up, assumed;
                    do {
                        assumed = cur;
                        cur = atomicCAS(up, assumed,
                                        __float_as_uint(__uint_as_float(assumed) * f));
                    } while (cur != assumed);
                    atomicOr(&pend[tgt], 0x80000000u);
                }
                unsigned old = atomicSub(&pend[tgt], 1u);
                if ((old & 0x7fffffffu) == 1u) {
                    unsigned pv = *(volatile unsigned*)&pend[tgt];
                    float P = __uint_as_float(*(volatile unsigned*)&A1[tgt]);
                    unsigned char st = ((pv & 0x80000000u) && P < SCORE_FLOOR) ? 2 : 1;
                    state8[tgt] = st;
                    out[tgt] = P;
                    out[N + tgt] = (st == 1) ? 1.0f : 0.0f;
                    if (starts16[tgt] != starts16[tgt + 1]) {
                        int p = atomicAdd(&qt, 1);
                        queue[p] = (unsigned short)tgt;
                    }
                }
            }
        }
        __syncthreads();
        if (tid == 0) qh = t;
        __syncthreads();
    }
}

extern "C" void kernel_launch(void* const* d_in, const int* in_sizes, int n_in,
                              void* d_out, int out_size, void* d_ws, size_t ws_size,
                              hipStream_t stream) {
    const float4* boxes = (const float4*)d_in[0];
    const float* scores = (const float*)d_in[1];
    float* out = (float*)d_out;
    char* ws = (char*)d_ws;

    float4* t4 = (float4*)ws;                 // 64B
    int* counter = (int*)(ws + 64);           // 4B
    int2* adj = (int2*)(ws + 4096);

    long long avail = ((long long)ws_size - 4096) / 8;
    if (avail < 0) avail = 0;
    int cap = TCAP;
    if (avail < cap) cap = (int)avail;

    hipLaunchKernelGGL(k_top4, dim3(1), dim3(256), 0, stream, scores, boxes, t4, counter);
    hipLaunchKernelGGL(k_pairs, dim3(32, 32), dim3(256), 0, stream,
                       boxes, scores, t4, counter, adj, cap);
    hipLaunchKernelGGL(k_nms, dim3(1), dim3(512), 0, stream,
                       adj, counter, scores, out, cap);
}